// Round 21
// baseline (360.584 us; speedup 1.0000x reference)
//
#include <hip/hip_runtime.h>

typedef __attribute__((ext_vector_type(4))) float f32x4;
typedef __attribute__((ext_vector_type(8))) short bf16x8;
typedef __attribute__((ext_vector_type(4))) unsigned int u32x4;

#define MFMA32 __builtin_amdgcn_mfma_f32_16x16x32_bf16

__device__ __forceinline__ unsigned short f2bf(float f) {
  unsigned int u = __float_as_uint(f);
  return (unsigned short)((u + 0x7FFFu + ((u >> 16) & 1u)) >> 16);
}
// round-half-up bf16 pack: 3 VALU ops (2 adds + v_perm), max err 0.5 ulp
__device__ __forceinline__ unsigned int pack2(float a, float b) {
  return __builtin_amdgcn_perm(__float_as_uint(b) + 0x8000u,
                               __float_as_uint(a) + 0x8000u, 0x07060302u);
}
__device__ __forceinline__ bf16x8 mk8(unsigned int a, unsigned int b,
                                      unsigned int c, unsigned int d) {
  u32x4 u = {a, b, c, d};
  return __builtin_bit_cast(bf16x8, u);
}
// 512B rows: XOR byte bits 4..6 with ((tok>>3)^tok)&7
__device__ __forceinline__ int xsw(int tok, int cb) {
  return (tok * 512 + cb) ^ ((((tok >> 3) ^ tok) & 7) << 4);
}

__global__ void convw_kernel(const float* __restrict__ wqkv,
                             const float* __restrict__ wout,
                             unsigned short* __restrict__ dst) {
  int i = blockIdx.x * 256 + threadIdx.x;
  if (i < 196608) dst[i] = f2bf(wqkv[i]);
  if (i < 65536) dst[196608 + i] = f2bf(wout[i]);
}

__global__ __launch_bounds__(256, 2) void wattn_kernel(
    const float* __restrict__ x, const unsigned short* __restrict__ wqkv,
    const unsigned short* __restrict__ wout, const float* __restrict__ bo,
    float* __restrict__ y) {
  __shared__ __align__(16) char lds[65536];   // XS0 [0,32K) XS1 [32K,64K), each aliased as AT after use

  const int tid = threadIdx.x;
  const int l = tid & 63;
  const int w = tid >> 6;      // wave 0..3
  const int lo = l & 15;
  const int dg = l >> 4;       // 0..3

  // XCD-chunked block swizzle over window-pairs (bijective: 2048 = 8*256)
  const int bid = blockIdx.x;
  const int rw = ((bid & 7) << 8) | (bid >> 3);
  const int b = rw >> 9;
  const int rem = rw & 511;
  const int wy = rem >> 4;
  const int wxp = rem & 15;    // pair index: windows wx = 2*wxp, 2*wxp+1

  const size_t wbase = (size_t)b * 16777216 + (size_t)wy * 2048 + (size_t)wxp * 16;
  const float* xw = x + wbase;
  float* yw = y + wbase;

  // ---- stage both windows -> XS0/XS1 [tok][c] bf16 ----
#pragma unroll 1
  for (int wsel = 0; wsel < 2; ++wsel) {
    char* XSb = lds + wsel * 32768;
    const int irow = lo >> 1;
    const int jq = lo & 1;
    const float* xp = xw + wsel * 8 + irow * 256 + jq * 4;
    const int tok0 = irow * 8 + jq * 4;
#pragma unroll 2
    for (int cc = 0; cc < 4; ++cc) {
      const int cb = w * 64 + cc * 16 + dg * 4;
      f32x4 v0 = *(const f32x4*)(xp + (size_t)(cb + 0) * 65536);
      f32x4 v1 = *(const f32x4*)(xp + (size_t)(cb + 1) * 65536);
      f32x4 v2 = *(const f32x4*)(xp + (size_t)(cb + 2) * 65536);
      f32x4 v3 = *(const f32x4*)(xp + (size_t)(cb + 3) * 65536);
#pragma unroll
      for (int t = 0; t < 4; ++t) {
        uint2 uu;
        uu.x = pack2(v0[t], v1[t]);
        uu.y = pack2(v2[t], v3[t]);
        *(uint2*)(XSb + xsw(tok0 + t, cb * 2)) = uu;
      }
    }
  }
  __syncthreads();   // bar 1: staging complete

  const float lscale = 0.17677669529663687f * 1.4426950408889634f;

  // ---- per window: QKV + attention, then alias-write AT ----
#pragma unroll 1
  for (int wsel = 0; wsel < 2; ++wsel) {
    char* XSb = lds + wsel * 32768;
    unsigned int outp[2][2][4][2];   // [hh][dt][it][pair], hh compile-time

#pragma unroll
    for (int hh = 0; hh < 2; ++hh) {
      const int h = w * 2 + hh;
      const unsigned short* wp = wqkv + (size_t)(h * 32 + lo) * 256 + dg * 8;

      // Q-pass (qa[a][it]: d = a*16 + dg*4 + t, tok lane)
      bf16x8 qf[4], kf[4];
      {
        f32x4 qa[2][4];
#pragma unroll
        for (int a = 0; a < 2; ++a)
#pragma unroll
          for (int it = 0; it < 4; ++it) qa[a][it] = {0.f, 0.f, 0.f, 0.f};
        __builtin_amdgcn_s_setprio(1);
#pragma unroll 4
        for (int kk = 0; kk < 8; ++kk) {
          bf16x8 xf[4];
#pragma unroll
          for (int it = 0; it < 4; ++it)
            xf[it] = *(const bf16x8*)(XSb + xsw(it * 16 + lo, kk * 64 + dg * 16));
          bf16x8 wq0 = *(const bf16x8*)(wp + kk * 32);
          bf16x8 wq1 = *(const bf16x8*)(wp + 4096 + kk * 32);
#pragma unroll
          for (int it = 0; it < 4; ++it) {
            qa[0][it] = MFMA32(wq0, xf[it], qa[0][it], 0, 0, 0);
            qa[1][it] = MFMA32(wq1, xf[it], qa[1][it], 0, 0, 0);
          }
        }
        __builtin_amdgcn_s_setprio(0);
        // concat accs -> K=32 frags; position->d bijection identical for
        // qf/kf, so the d-scramble cancels inside S
#pragma unroll
        for (int it = 0; it < 4; ++it)
          qf[it] = mk8(pack2(qa[0][it][0], qa[0][it][1]), pack2(qa[0][it][2], qa[0][it][3]),
                       pack2(qa[1][it][0], qa[1][it][1]), pack2(qa[1][it][2], qa[1][it][3]));
      }
      // K-pass
      {
        f32x4 ka[2][4];
#pragma unroll
        for (int a = 0; a < 2; ++a)
#pragma unroll
          for (int it = 0; it < 4; ++it) ka[a][it] = {0.f, 0.f, 0.f, 0.f};
        __builtin_amdgcn_s_setprio(1);
#pragma unroll 4
        for (int kk = 0; kk < 8; ++kk) {
          bf16x8 xf[4];
#pragma unroll
          for (int it = 0; it < 4; ++it)
            xf[it] = *(const bf16x8*)(XSb + xsw(it * 16 + lo, kk * 64 + dg * 16));
          bf16x8 wk0 = *(const bf16x8*)(wp + 65536 + kk * 32);
          bf16x8 wk1 = *(const bf16x8*)(wp + 69632 + kk * 32);
#pragma unroll
          for (int it = 0; it < 4; ++it) {
            ka[0][it] = MFMA32(wk0, xf[it], ka[0][it], 0, 0, 0);
            ka[1][it] = MFMA32(wk1, xf[it], ka[1][it], 0, 0, 0);
          }
        }
        __builtin_amdgcn_s_setprio(0);
#pragma unroll
        for (int it = 0; it < 4; ++it)
          kf[it] = mk8(pack2(ka[0][it][0], ka[0][it][1]), pack2(ka[0][it][2], ka[0][it][3]),
                       pack2(ka[1][it][0], ka[1][it][1]), pack2(ka[1][it][2], ka[1][it][3]));
      }
      // V-pass (va[tb][dt]: tok = tb*16+dg*4+t, d = dt*16+lo)
      bf16x8 vf[2][2];
      {
        f32x4 va[4][2];
#pragma unroll
        for (int tb = 0; tb < 4; ++tb)
#pragma unroll
          for (int dt = 0; dt < 2; ++dt) va[tb][dt] = {0.f, 0.f, 0.f, 0.f};
        __builtin_amdgcn_s_setprio(1);
#pragma unroll 4
        for (int kk = 0; kk < 8; ++kk) {
          bf16x8 xf[4];
#pragma unroll
          for (int tb = 0; tb < 4; ++tb)
            xf[tb] = *(const bf16x8*)(XSb + xsw(tb * 16 + lo, kk * 64 + dg * 16));
          bf16x8 wv0 = *(const bf16x8*)(wp + 131072 + kk * 32);
          bf16x8 wv1 = *(const bf16x8*)(wp + 135168 + kk * 32);
#pragma unroll
          for (int tb = 0; tb < 4; ++tb) {
            va[tb][0] = MFMA32(xf[tb], wv0, va[tb][0], 0, 0, 0);
            va[tb][1] = MFMA32(xf[tb], wv1, va[tb][1], 0, 0, 0);
          }
        }
        __builtin_amdgcn_s_setprio(0);
        // vf[sb][dt]: position->tok map shared with pp -> cancels in PV
#pragma unroll
        for (int sb = 0; sb < 2; ++sb)
#pragma unroll
          for (int dt = 0; dt < 2; ++dt)
            vf[sb][dt] = mk8(pack2(va[2 * sb][dt][0], va[2 * sb][dt][1]),
                             pack2(va[2 * sb][dt][2], va[2 * sb][dt][3]),
                             pack2(va[2 * sb + 1][dt][0], va[2 * sb + 1][dt][1]),
                             pack2(va[2 * sb + 1][dt][2], va[2 * sb + 1][dt][3]));
      }

      // per i-tile: S^T, no-max softmax, PV — register-resident
#pragma unroll
      for (int it = 0; it < 4; ++it) {
        f32x4 stt[4];   // stt[jt][t] = S^T[j = jt*16+dg*4+t][i = it*16+lo]
        __builtin_amdgcn_s_setprio(1);
#pragma unroll
        for (int jt = 0; jt < 4; ++jt) {
          f32x4 z = {0.f, 0.f, 0.f, 0.f};
          stt[jt] = MFMA32(kf[jt], qf[it], z, 0, 0, 0);
        }
        __builtin_amdgcn_s_setprio(0);
        // logits ~ N(0,1): exp2 args bounded -> skip max-subtraction;
        // P unnormalized (bounded), rs applied after PV
        float s = 0.f;
#pragma unroll
        for (int jt = 0; jt < 4; ++jt)
#pragma unroll
          for (int t = 0; t < 4; ++t) {
            float e = exp2f(stt[jt][t] * lscale);
            stt[jt][t] = e;
            s += e;
          }
        s += __shfl_xor(s, 16, 64);
        s += __shfl_xor(s, 32, 64);
        const float rs = 1.0f / s;

        bf16x8 pp0 = mk8(pack2(stt[0][0], stt[0][1]), pack2(stt[0][2], stt[0][3]),
                         pack2(stt[1][0], stt[1][1]), pack2(stt[1][2], stt[1][3]));
        bf16x8 pp1 = mk8(pack2(stt[2][0], stt[2][1]), pack2(stt[2][2], stt[2][3]),
                         pack2(stt[3][0], stt[3][1]), pack2(stt[3][2], stt[3][3]));
        __builtin_amdgcn_s_setprio(1);
#pragma unroll
        for (int dt = 0; dt < 2; ++dt) {
          f32x4 z = {0.f, 0.f, 0.f, 0.f};
          f32x4 o = MFMA32(vf[0][dt], pp0, z, 0, 0, 0);   // out^T[d][i]
          o = MFMA32(vf[1][dt], pp1, o, 0, 0, 0);
          o *= rs;
          outp[hh][dt][it][0] = pack2(o[0], o[1]);
          outp[hh][dt][it][1] = pack2(o[2], o[3]);
        }
        __builtin_amdgcn_s_setprio(0);
      }
    }

    __syncthreads();   // all XS(wsel) reads done -> safe to alias as AT(wsel)

#pragma unroll
    for (int hh = 0; hh < 2; ++hh) {
      const int h = w * 2 + hh;
#pragma unroll
      for (int dt = 0; dt < 2; ++dt)
#pragma unroll
        for (int it = 0; it < 4; ++it) {
          uint2 uu;
          uu.x = outp[hh][dt][it][0];
          uu.y = outp[hh][dt][it][1];
          *(uint2*)(XSb + xsw(it * 16 + lo, h * 64 + dt * 32 + dg * 8)) = uu;
        }
    }
  }
  __syncthreads();   // AT0+AT1 complete

  // ---- paired final projection: both windows share each weight fragment;
  //      stores complete full 64B segments (win0 floats [0..7] + win1 [8..15])
#pragma unroll 1
  for (int oq = 0; oq < 4; ++oq) {
    const unsigned short* wo0 =
        wout + (size_t)(w * 64 + oq * 16 + lo) * 256 + dg * 8;
    f32x4 ya0[4], ya1[4];
#pragma unroll
    for (int it = 0; it < 4; ++it) {
      ya0[it] = {0.f, 0.f, 0.f, 0.f};
      ya1[it] = {0.f, 0.f, 0.f, 0.f};
    }
    __builtin_amdgcn_s_setprio(1);
#pragma unroll 2
    for (int kk = 0; kk < 8; ++kk) {
      bf16x8 wf = *(const bf16x8*)(wo0 + kk * 32);
#pragma unroll
      for (int it = 0; it < 4; ++it) {
        bf16x8 b0 = *(const bf16x8*)(lds + xsw(it * 16 + lo, kk * 64 + dg * 16));
        bf16x8 b1 = *(const bf16x8*)(lds + 32768 + xsw(it * 16 + lo, kk * 64 + dg * 16));
        ya0[it] = MFMA32(b0, wf, ya0[it], 0, 0, 0);
        ya1[it] = MFMA32(b1, wf, ya1[it], 0, 0, 0);
      }
    }
    __builtin_amdgcn_s_setprio(0);
    const int orow = w * 64 + oq * 16 + lo;
    const float bv = bo[orow];
#pragma unroll
    for (int it = 0; it < 4; ++it) {
      f32x4 r0 = ya0[it];
      f32x4 r1 = ya1[it];
      r0[0] += bv; r0[1] += bv; r0[2] += bv; r0[3] += bv;
      r1[0] += bv; r1[1] += bv; r1[2] += bv; r1[3] += bv;
      const int tok0 = it * 16 + dg * 4;
      float* dst = yw + (size_t)orow * 65536 +
                   (size_t)(tok0 >> 3) * 256 + (tok0 & 7);
      *(f32x4*)dst = r0;          // win0: floats [0..7] half of 64B
      *(f32x4*)(dst + 8) = r1;    // win1: floats [8..15] -> full line
    }
  }
}

extern "C" void kernel_launch(void* const* d_in, const int* in_sizes, int n_in,
                              void* d_out, int out_size, void* d_ws, size_t ws_size,
                              hipStream_t stream) {
  const float* x = (const float*)d_in[0];
  const float* wqkv = (const float*)d_in[1];
  const float* wout = (const float*)d_in[2];
  const float* bo = (const float*)d_in[3];
  float* y = (float*)d_out;
  unsigned short* wbf = (unsigned short*)d_ws;

  convw_kernel<<<768, 256, 0, stream>>>(wqkv, wout, wbf);
  wattn_kernel<<<2048, 256, 0, stream>>>(x, wbf, wbf + 196608, bo, y);
}

// Round 22
// 351.908 us; speedup vs baseline: 1.0247x; 1.0247x over previous
//
#include <hip/hip_runtime.h>

typedef __attribute__((ext_vector_type(4))) float f32x4;
typedef __attribute__((ext_vector_type(8))) short bf16x8;
typedef __attribute__((ext_vector_type(4))) unsigned int u32x4;

#define MFMA32 __builtin_amdgcn_mfma_f32_16x16x32_bf16

__device__ __forceinline__ unsigned short f2bf(float f) {
  unsigned int u = __float_as_uint(f);
  return (unsigned short)((u + 0x7FFFu + ((u >> 16) & 1u)) >> 16);
}
// round-half-up bf16 pack: 3 VALU ops (2 adds + v_perm), max err 0.5 ulp
__device__ __forceinline__ unsigned int pack2(float a, float b) {
  return __builtin_amdgcn_perm(__float_as_uint(b) + 0x8000u,
                               __float_as_uint(a) + 0x8000u, 0x07060302u);
}
__device__ __forceinline__ bf16x8 mk8(unsigned int a, unsigned int b,
                                      unsigned int c, unsigned int d) {
  u32x4 u = {a, b, c, d};
  return __builtin_bit_cast(bf16x8, u);
}
// 512B rows: XOR byte bits 4..6 with ((tok>>3)^tok)&7
__device__ __forceinline__ int xsw(int tok, int cb) {
  return (tok * 512 + cb) ^ ((((tok >> 3) ^ tok) & 7) << 4);
}

__global__ void convw_kernel(const float* __restrict__ wqkv,
                             const float* __restrict__ wout,
                             unsigned short* __restrict__ dst) {
  int i = blockIdx.x * 256 + threadIdx.x;
  if (i < 196608) dst[i] = f2bf(wqkv[i]);
  if (i < 65536) dst[196608 + i] = f2bf(wout[i]);
}

__global__ __launch_bounds__(256, 2) void wattn_kernel(
    const float* __restrict__ x, const unsigned short* __restrict__ wqkv,
    const unsigned short* __restrict__ wout, const float* __restrict__ bo,
    float* __restrict__ y) {
  __shared__ __align__(16) char lds[65536];   // XS0 [0,32K) XS1 [32K,64K), each aliased as AT after use

  const int tid = threadIdx.x;
  const int l = tid & 63;
  const int w = tid >> 6;      // wave 0..3
  const int lo = l & 15;
  const int dg = l >> 4;       // 0..3

  // XCD-chunked block swizzle over window-pairs (bijective: 2048 = 8*256)
  const int bid = blockIdx.x;
  const int rw = ((bid & 7) << 8) | (bid >> 3);
  const int b = rw >> 9;
  const int rem = rw & 511;
  const int wy = rem >> 4;
  const int wxp = rem & 15;    // pair index: windows wx = 2*wxp, 2*wxp+1

  const size_t wbase = (size_t)b * 16777216 + (size_t)wy * 2048 + (size_t)wxp * 16;
  const float* xw = x + wbase;
  float* yw = y + wbase;

  // ---- stage both windows -> XS0/XS1 [tok][c] bf16 ----
#pragma unroll 1
  for (int wsel = 0; wsel < 2; ++wsel) {
    char* XSb = lds + wsel * 32768;
    const int irow = lo >> 1;
    const int jq = lo & 1;
    const float* xp = xw + wsel * 8 + irow * 256 + jq * 4;
    const int tok0 = irow * 8 + jq * 4;
#pragma unroll 2
    for (int cc = 0; cc < 4; ++cc) {
      const int cb = w * 64 + cc * 16 + dg * 4;
      f32x4 v0 = *(const f32x4*)(xp + (size_t)(cb + 0) * 65536);
      f32x4 v1 = *(const f32x4*)(xp + (size_t)(cb + 1) * 65536);
      f32x4 v2 = *(const f32x4*)(xp + (size_t)(cb + 2) * 65536);
      f32x4 v3 = *(const f32x4*)(xp + (size_t)(cb + 3) * 65536);
#pragma unroll
      for (int t = 0; t < 4; ++t) {
        uint2 uu;
        uu.x = pack2(v0[t], v1[t]);
        uu.y = pack2(v2[t], v3[t]);
        *(uint2*)(XSb + xsw(tok0 + t, cb * 2)) = uu;
      }
    }
  }
  __syncthreads();   // bar 1: staging complete

  const float lscale = 0.17677669529663687f * 1.4426950408889634f;

  // ---- per window: QKV + attention, then alias-write AT ----
#pragma unroll 1
  for (int wsel = 0; wsel < 2; ++wsel) {
    char* XSb = lds + wsel * 32768;
    unsigned int outp[2][2][4][2];   // [hh][dt][it][pair], hh compile-time

#pragma unroll
    for (int hh = 0; hh < 2; ++hh) {
      const int h = w * 2 + hh;
      const unsigned short* wp = wqkv + (size_t)(h * 32 + lo) * 256 + dg * 8;

      // Q-pass (qa[a][it]: d = a*16 + dg*4 + t, tok lane)
      bf16x8 qf[4], kf[4];
      {
        f32x4 qa[2][4];
#pragma unroll
        for (int a = 0; a < 2; ++a)
#pragma unroll
          for (int it = 0; it < 4; ++it) qa[a][it] = {0.f, 0.f, 0.f, 0.f};
#pragma unroll 4
        for (int kk = 0; kk < 8; ++kk) {
          bf16x8 xf[4];
#pragma unroll
          for (int it = 0; it < 4; ++it)
            xf[it] = *(const bf16x8*)(XSb + xsw(it * 16 + lo, kk * 64 + dg * 16));
          bf16x8 wq0 = *(const bf16x8*)(wp + kk * 32);
          bf16x8 wq1 = *(const bf16x8*)(wp + 4096 + kk * 32);
#pragma unroll
          for (int it = 0; it < 4; ++it) {
            qa[0][it] = MFMA32(wq0, xf[it], qa[0][it], 0, 0, 0);
            qa[1][it] = MFMA32(wq1, xf[it], qa[1][it], 0, 0, 0);
          }
        }
        // concat accs -> K=32 frags; position->d bijection identical for
        // qf/kf, so the d-scramble cancels inside S
#pragma unroll
        for (int it = 0; it < 4; ++it)
          qf[it] = mk8(pack2(qa[0][it][0], qa[0][it][1]), pack2(qa[0][it][2], qa[0][it][3]),
                       pack2(qa[1][it][0], qa[1][it][1]), pack2(qa[1][it][2], qa[1][it][3]));
      }
      // K-pass
      {
        f32x4 ka[2][4];
#pragma unroll
        for (int a = 0; a < 2; ++a)
#pragma unroll
          for (int it = 0; it < 4; ++it) ka[a][it] = {0.f, 0.f, 0.f, 0.f};
#pragma unroll 4
        for (int kk = 0; kk < 8; ++kk) {
          bf16x8 xf[4];
#pragma unroll
          for (int it = 0; it < 4; ++it)
            xf[it] = *(const bf16x8*)(XSb + xsw(it * 16 + lo, kk * 64 + dg * 16));
          bf16x8 wk0 = *(const bf16x8*)(wp + 65536 + kk * 32);
          bf16x8 wk1 = *(const bf16x8*)(wp + 69632 + kk * 32);
#pragma unroll
          for (int it = 0; it < 4; ++it) {
            ka[0][it] = MFMA32(wk0, xf[it], ka[0][it], 0, 0, 0);
            ka[1][it] = MFMA32(wk1, xf[it], ka[1][it], 0, 0, 0);
          }
        }
#pragma unroll
        for (int it = 0; it < 4; ++it)
          kf[it] = mk8(pack2(ka[0][it][0], ka[0][it][1]), pack2(ka[0][it][2], ka[0][it][3]),
                       pack2(ka[1][it][0], ka[1][it][1]), pack2(ka[1][it][2], ka[1][it][3]));
      }
      // V-pass (va[tb][dt]: tok = tb*16+dg*4+t, d = dt*16+lo)
      bf16x8 vf[2][2];
      {
        f32x4 va[4][2];
#pragma unroll
        for (int tb = 0; tb < 4; ++tb)
#pragma unroll
          for (int dt = 0; dt < 2; ++dt) va[tb][dt] = {0.f, 0.f, 0.f, 0.f};
#pragma unroll 4
        for (int kk = 0; kk < 8; ++kk) {
          bf16x8 xf[4];
#pragma unroll
          for (int tb = 0; tb < 4; ++tb)
            xf[tb] = *(const bf16x8*)(XSb + xsw(tb * 16 + lo, kk * 64 + dg * 16));
          bf16x8 wv0 = *(const bf16x8*)(wp + 131072 + kk * 32);
          bf16x8 wv1 = *(const bf16x8*)(wp + 135168 + kk * 32);
#pragma unroll
          for (int tb = 0; tb < 4; ++tb) {
            va[tb][0] = MFMA32(xf[tb], wv0, va[tb][0], 0, 0, 0);
            va[tb][1] = MFMA32(xf[tb], wv1, va[tb][1], 0, 0, 0);
          }
        }
        // vf[sb][dt]: position->tok map shared with pp -> cancels in PV
#pragma unroll
        for (int sb = 0; sb < 2; ++sb)
#pragma unroll
          for (int dt = 0; dt < 2; ++dt)
            vf[sb][dt] = mk8(pack2(va[2 * sb][dt][0], va[2 * sb][dt][1]),
                             pack2(va[2 * sb][dt][2], va[2 * sb][dt][3]),
                             pack2(va[2 * sb + 1][dt][0], va[2 * sb + 1][dt][1]),
                             pack2(va[2 * sb + 1][dt][2], va[2 * sb + 1][dt][3]));
      }

      // per i-tile: S^T, no-max softmax, PV — register-resident
#pragma unroll
      for (int it = 0; it < 4; ++it) {
        f32x4 stt[4];   // stt[jt][t] = S^T[j = jt*16+dg*4+t][i = it*16+lo]
#pragma unroll
        for (int jt = 0; jt < 4; ++jt) {
          f32x4 z = {0.f, 0.f, 0.f, 0.f};
          stt[jt] = MFMA32(kf[jt], qf[it], z, 0, 0, 0);
        }
        // logits ~ N(0,1): exp2 args bounded -> skip max-subtraction;
        // P unnormalized (bounded), rs applied after PV
        float s = 0.f;
#pragma unroll
        for (int jt = 0; jt < 4; ++jt)
#pragma unroll
          for (int t = 0; t < 4; ++t) {
            float e = exp2f(stt[jt][t] * lscale);
            stt[jt][t] = e;
            s += e;
          }
        s += __shfl_xor(s, 16, 64);
        s += __shfl_xor(s, 32, 64);
        const float rs = 1.0f / s;

        bf16x8 pp0 = mk8(pack2(stt[0][0], stt[0][1]), pack2(stt[0][2], stt[0][3]),
                         pack2(stt[1][0], stt[1][1]), pack2(stt[1][2], stt[1][3]));
        bf16x8 pp1 = mk8(pack2(stt[2][0], stt[2][1]), pack2(stt[2][2], stt[2][3]),
                         pack2(stt[3][0], stt[3][1]), pack2(stt[3][2], stt[3][3]));
#pragma unroll
        for (int dt = 0; dt < 2; ++dt) {
          f32x4 z = {0.f, 0.f, 0.f, 0.f};
          f32x4 o = MFMA32(vf[0][dt], pp0, z, 0, 0, 0);   // out^T[d][i]
          o = MFMA32(vf[1][dt], pp1, o, 0, 0, 0);
          o *= rs;
          outp[hh][dt][it][0] = pack2(o[0], o[1]);
          outp[hh][dt][it][1] = pack2(o[2], o[3]);
        }
      }
    }

    __syncthreads();   // all XS(wsel) reads done -> safe to alias as AT(wsel)

#pragma unroll
    for (int hh = 0; hh < 2; ++hh) {
      const int h = w * 2 + hh;
#pragma unroll
      for (int dt = 0; dt < 2; ++dt)
#pragma unroll
        for (int it = 0; it < 4; ++it) {
          uint2 uu;
          uu.x = outp[hh][dt][it][0];
          uu.y = outp[hh][dt][it][1];
          *(uint2*)(XSb + xsw(it * 16 + lo, h * 64 + dt * 32 + dg * 8)) = uu;
        }
    }
  }
  __syncthreads();   // AT0+AT1 complete

  // ---- paired final projection: both windows share each weight fragment;
  //      stores complete full 64B segments (win0 floats [0..7] + win1 [8..15])
#pragma unroll 1
  for (int oq = 0; oq < 4; ++oq) {
    const unsigned short* wo0 =
        wout + (size_t)(w * 64 + oq * 16 + lo) * 256 + dg * 8;
    f32x4 ya0[4], ya1[4];
#pragma unroll
    for (int it = 0; it < 4; ++it) {
      ya0[it] = {0.f, 0.f, 0.f, 0.f};
      ya1[it] = {0.f, 0.f, 0.f, 0.f};
    }
#pragma unroll 2
    for (int kk = 0; kk < 8; ++kk) {
      bf16x8 wf = *(const bf16x8*)(wo0 + kk * 32);
#pragma unroll
      for (int it = 0; it < 4; ++it) {
        bf16x8 b0 = *(const bf16x8*)(lds + xsw(it * 16 + lo, kk * 64 + dg * 16));
        bf16x8 b1 = *(const bf16x8*)(lds + 32768 + xsw(it * 16 + lo, kk * 64 + dg * 16));
        ya0[it] = MFMA32(b0, wf, ya0[it], 0, 0, 0);
        ya1[it] = MFMA32(b1, wf, ya1[it], 0, 0, 0);
      }
    }
    const int orow = w * 64 + oq * 16 + lo;
    const float bv = bo[orow];
#pragma unroll
    for (int it = 0; it < 4; ++it) {
      f32x4 r0 = ya0[it];
      f32x4 r1 = ya1[it];
      r0[0] += bv; r0[1] += bv; r0[2] += bv; r0[3] += bv;
      r1[0] += bv; r1[1] += bv; r1[2] += bv; r1[3] += bv;
      const int tok0 = it * 16 + dg * 4;
      float* dst = yw + (size_t)orow * 65536 +
                   (size_t)(tok0 >> 3) * 256 + (tok0 & 7);
      *(f32x4*)dst = r0;          // win0: floats [0..7] half of 64B
      *(f32x4*)(dst + 8) = r1;    // win1: floats [8..15] -> full line
    }
  }
}

extern "C" void kernel_launch(void* const* d_in, const int* in_sizes, int n_in,
                              void* d_out, int out_size, void* d_ws, size_t ws_size,
                              hipStream_t stream) {
  const float* x = (const float*)d_in[0];
  const float* wqkv = (const float*)d_in[1];
  const float* wout = (const float*)d_in[2];
  const float* bo = (const float*)d_in[3];
  float* y = (float*)d_out;
  unsigned short* wbf = (unsigned short*)d_ws;

  convw_kernel<<<768, 256, 0, stream>>>(wqkv, wout, wbf);
  wattn_kernel<<<2048, 256, 0, stream>>>(x, wbf, wbf + 196608, bo, y);
}